// Round 11
// baseline (18.447 us; speedup 1.0000x reference)
//
#include <hip/hip_runtime.h>

#define NF 17
#define NN 23
#define ED 16
#define BLK 1024
#define RPP 256      // rows per pass = BLK/4
#define RPB 512      // rows per block (2 passes); grid*RPB == nrows exactly
#define SROWS 862    // packed rows of the 14 small-vocab fields
#define SSTR 20      // padded floats per LDS row (80 B)

typedef int   int4u    __attribute__((ext_vector_type(4), aligned(4)));
typedef float float4u  __attribute__((ext_vector_type(4), aligned(4)));
typedef float float2u  __attribute__((ext_vector_type(2), aligned(4)));
typedef float float2v  __attribute__((ext_vector_type(2)));

// broadcast int k (0..15) of the row from its owner lane to all 4 lanes of the
// group: owner lane = (lane & ~3) | (k>>2), register slot = k&3.
// BitMode ds_swizzle: offset = (xor<<10) | (or<<5) | and; and=0x1C keeps the
// group bits, or = k>>2 selects the source lane within the group.
#define SWZ(slotval, j) __builtin_amdgcn_ds_swizzle((slotval), ((j) << 5) | 0x1C)

// packed accumulate: 2x v_pk_add_f32 + 2x v_pk_fma_f32 per field
__device__ __forceinline__ void acc4(const float4 v, float2v& sa, float2v& sb,
                                     float2v& sq2) {
    const float2v lo = {v.x, v.y};
    const float2v hi = {v.z, v.w};
    sa += lo;
    sb += hi;
    sq2 += lo * lo;
    sq2 += hi * hi;
}

__global__ __launch_bounds__(BLK, 8) void ffm_fwd_kernel(
    const int* __restrict__ x_cat,
    const float* __restrict__ x_num,
    const float* __restrict__ table,
    const float* __restrict__ W_num,
    const float* __restrict__ bias,
    float* __restrict__ out,
    int nrows)
{
    __shared__ float tab[SROWS * SSTR];   // 68,960 B -> 2 blocks/CU
    __shared__ float wsum[24];            // padded; wsum[23] = 0

    const int tid = threadIdx.x;
    const int rl  = tid >> 2;   // local row within pass
    const int g   = tid & 3;    // dim-group: dims [4g, 4g+4)
    const int wb  = 6 * g;

    const int row0 = blockIdx.x * RPB + rl;    // grid*RPB == nrows, no guards
    const int row1 = row0 + RPP;

    // ---- Pass-0 x_cat: lane-split load (ints [4g,4g+4)) + all-lane int16 ----
    const int* xc0 = x_cat + (size_t)row0 * NF;
    const int4u av = *(const int4u*)(xc0 + g * 4);
    const int  a16 = xc0[16];

    // broadcast the 3 gather indices first so the gathers issue early
    const int bc4  = SWZ(av.x, 1);   // field 4  (k=4:  slot 0, lane 1)
    const int bc10 = SWZ(av.z, 2);   // field 10 (k=10: slot 2, lane 2)
    const int bc14 = SWZ(av.z, 3);   // field 14 (k=14: slot 2, lane 3)
    const float4 gv00 = *(const float4*)(table + (size_t)(bc4  +     653) * ED + g * 4);
    const float4 gv01 = *(const float4*)(table + (size_t)(bc10 + 1000787) * ED + g * 4);
    const float4 gv02 = *(const float4*)(table + (size_t)(bc14 + 1001846) * ED + g * 4);

    // remaining 13 broadcasts for the small fields
    const int bc0  = SWZ(av.x, 0);
    const int bc1  = SWZ(av.y, 0);
    const int bc2  = SWZ(av.z, 0);
    const int bc3  = SWZ(av.w, 0);
    const int bc5  = SWZ(av.y, 1);
    const int bc6  = SWZ(av.z, 1);
    const int bc7  = SWZ(av.w, 1);
    const int bc8  = SWZ(av.x, 2);
    const int bc9  = SWZ(av.y, 2);
    const int bc11 = SWZ(av.w, 2);
    const int bc12 = SWZ(av.x, 3);
    const int bc13 = SWZ(av.y, 3);
    const int bc15 = SWZ(av.w, 3);

    const float* xp0 = x_num + (size_t)row0 * NN;
    const float4u xa0 = *(const float4u*)(xp0 + wb);
    float xb0_0, xb1_0;
    if (g < 3) { const float2u t = *(const float2u*)(xp0 + wb + 4); xb0_0 = t.x; xb1_0 = t.y; }
    else       { xb0_0 = xp0[22]; xb1_0 = 0.f; }

    if (tid < 24) {
        float a = 0.f;
        if (tid < NN) {
            #pragma unroll
            for (int d = 0; d < ED; ++d) a += W_num[d * NN + tid];
        }
        wsum[tid] = a;
    }

    // ---- Stage the 14 small-vocab fields (862 rows, 55 KB) once per block ----
    for (int i = tid; i < SROWS * 4; i += BLK) {
        const int r = i >> 2, q = i & 3;
        const int d = (r < 653) ? 0 : (r < 787) ? 1000000 : (r < 845) ? 1001001 : 1003001;
        *(float4*)&tab[r * SSTR + q * 4] =
            *(const float4*)(table + (size_t)(r + d) * ED + q * 4);
    }
    __syncthreads();

    const float b0 = bias[0];
    const float2v wp0 = {wsum[wb],     wsum[wb + 1]};
    const float2v wp1 = {wsum[wb + 2], wsum[wb + 3]};
    const float2v wp2 = {wsum[wb + 4], wsum[wb + 5]};

    // ---- Pass-1 x_cat: lane-split load + broadcasts ----
    const int* xc1 = x_cat + (size_t)row1 * NF;
    const int4u cv = *(const int4u*)(xc1 + g * 4);
    const int  c16 = xc1[16];

    // ---- Pass 0 math ----
    {
        float2v lv = {0.f, 0.f};
        lv += float2v{xa0.x, xa0.y} * wp0;
        lv += float2v{xa0.z, xa0.w} * wp1;
        lv += float2v{xb0_0, xb1_0} * wp2;

        int pr[14];
        pr[0]  = bc0;         pr[1]  = 500 + bc1;   pr[2]  = 550 + bc2;
        pr[3]  = 650 + bc3;   pr[4]  = 653 + bc5;   pr[5]  = 663 + bc6;
        pr[6]  = 683 + bc7;   pr[7]  = 783 + bc8;   pr[8]  = 785 + bc9;
        pr[9]  = 787 + bc11;  pr[10] = 791 + bc12;  pr[11] = 795 + bc13;
        pr[12] = 845 + bc15;  pr[13] = 855 + a16;

        float2v sa = {0.f, 0.f}, sb = {0.f, 0.f}, sq2 = {0.f, 0.f};
        #pragma unroll
        for (int k = 0; k < 14; ++k)
            acc4(*(const float4*)&tab[pr[k] * SSTR + g * 4], sa, sb, sq2);

        acc4(gv00, sa, sb, sq2);
        acc4(gv01, sa, sb, sq2);
        acc4(gv02, sa, sb, sq2);

        const float s0 = sa.x, s1 = sa.y, s2 = sb.x, s3 = sb.y;
        const float sq = sq2.x + sq2.y;
        float contrib = (s0 + s1 + s2 + s3) + (lv.x + lv.y)
                      + 0.5f * ((s0 * s0 + s1 * s1 + s2 * s2 + s3 * s3) - sq);
        contrib += __shfl_xor(contrib, 1);
        contrib += __shfl_xor(contrib, 2);
        if (g == 0) out[row0] = b0 + contrib;
    }

    // ---- Pass-1 broadcasts + gathers + x_num ----
    const int dc4  = SWZ(cv.x, 1);
    const int dc10 = SWZ(cv.z, 2);
    const int dc14 = SWZ(cv.z, 3);
    const float4 gv10 = *(const float4*)(table + (size_t)(dc4  +     653) * ED + g * 4);
    const float4 gv11 = *(const float4*)(table + (size_t)(dc10 + 1000787) * ED + g * 4);
    const float4 gv12 = *(const float4*)(table + (size_t)(dc14 + 1001846) * ED + g * 4);

    const int dc0  = SWZ(cv.x, 0);
    const int dc1  = SWZ(cv.y, 0);
    const int dc2  = SWZ(cv.z, 0);
    const int dc3  = SWZ(cv.w, 0);
    const int dc5  = SWZ(cv.y, 1);
    const int dc6  = SWZ(cv.z, 1);
    const int dc7  = SWZ(cv.w, 1);
    const int dc8  = SWZ(cv.x, 2);
    const int dc9  = SWZ(cv.y, 2);
    const int dc11 = SWZ(cv.w, 2);
    const int dc12 = SWZ(cv.x, 3);
    const int dc13 = SWZ(cv.y, 3);
    const int dc15 = SWZ(cv.w, 3);

    const float* xp1 = x_num + (size_t)row1 * NN;
    const float4u xa1 = *(const float4u*)(xp1 + wb);
    float xb0_1, xb1_1;
    if (g < 3) { const float2u t = *(const float2u*)(xp1 + wb + 4); xb0_1 = t.x; xb1_1 = t.y; }
    else       { xb0_1 = xp1[22]; xb1_1 = 0.f; }

    // ---- Pass 1 math ----
    {
        float2v lv = {0.f, 0.f};
        lv += float2v{xa1.x, xa1.y} * wp0;
        lv += float2v{xa1.z, xa1.w} * wp1;
        lv += float2v{xb0_1, xb1_1} * wp2;

        int pr[14];
        pr[0]  = dc0;         pr[1]  = 500 + dc1;   pr[2]  = 550 + dc2;
        pr[3]  = 650 + dc3;   pr[4]  = 653 + dc5;   pr[5]  = 663 + dc6;
        pr[6]  = 683 + dc7;   pr[7]  = 783 + dc8;   pr[8]  = 785 + dc9;
        pr[9]  = 787 + dc11;  pr[10] = 791 + dc12;  pr[11] = 795 + dc13;
        pr[12] = 845 + dc15;  pr[13] = 855 + c16;

        float2v sa = {0.f, 0.f}, sb = {0.f, 0.f}, sq2 = {0.f, 0.f};
        #pragma unroll
        for (int k = 0; k < 14; ++k)
            acc4(*(const float4*)&tab[pr[k] * SSTR + g * 4], sa, sb, sq2);

        acc4(gv10, sa, sb, sq2);
        acc4(gv11, sa, sb, sq2);
        acc4(gv12, sa, sb, sq2);

        const float s0 = sa.x, s1 = sa.y, s2 = sb.x, s3 = sb.y;
        const float sq = sq2.x + sq2.y;
        float contrib = (s0 + s1 + s2 + s3) + (lv.x + lv.y)
                      + 0.5f * ((s0 * s0 + s1 * s1 + s2 * s2 + s3 * s3) - sq);
        contrib += __shfl_xor(contrib, 1);
        contrib += __shfl_xor(contrib, 2);
        if (g == 0) out[row1] = b0 + contrib;
    }
}

extern "C" void kernel_launch(void* const* d_in, const int* in_sizes, int n_in,
                              void* d_out, int out_size, void* d_ws, size_t ws_size,
                              hipStream_t stream) {
    const int*   x_cat = (const int*)  d_in[0];
    const float* x_num = (const float*)d_in[1];
    const float* table = (const float*)d_in[2];
    const float* W_num = (const float*)d_in[3];
    const float* bias  = (const float*)d_in[4];
    float* out = (float*)d_out;

    const int nrows = out_size;                 // 262144
    const int grid = (nrows + RPB - 1) / RPB;   // 512
    ffm_fwd_kernel<<<grid, BLK, 0, stream>>>(x_cat, x_num, table, W_num, bias, out, nrows);
}